// Round 7
// baseline (338.335 us; speedup 1.0000x reference)
//
#include <hip/hip_runtime.h>
#include <stdint.h>

// ConvMemory v8: out = (3x3 conv of E=exp(x), W=memory) / (3x3 boxsum of chan-sum(E))
// Zero-padding before softmax => OOB taps contribute exp(0)=1 to num & denom.
// Fused convf, 8x16 tile, 512 thr (8 waves), 1024 blocks (XCD-chunk swizzled).
// v8 KEY CHANGE vs v7: NO register arrays in the K-loop (rule #20: runtime-
// indexed register arrays -> scratch). Named slots W0..W5 / E00..E21 / a0,a1;
// 6-step groups (5 full + tail), every register identity compile-time; runtime
// kc only in ADDRESS arithmetic. W slots issued at kernel entry (fly during
// staging). Single barrier, shfl-S, inline Zinv (all bit-verified 6 rounds).

#define Cn 64
#define Hn 128
#define Wn 128
#define OC 128
#define HW (Hn * Wn)

typedef __attribute__((ext_vector_type(8))) short bf16x8_t;
typedef __attribute__((ext_vector_type(16))) float f32x16_t;

__device__ inline unsigned short f2bf(float f) {
    union { float f; uint32_t u; } v; v.f = f;
    uint32_t u = v.u;
    u += 0x7fffu + ((u >> 16) & 1u);
    return (unsigned short)(u >> 16);
}
__device__ inline float bf_lo(uint32_t u) {
    union { uint32_t u; float f; } v; v.u = u << 16;
    return v.f;
}
__device__ inline float bf_hi(uint32_t u) {
    union { uint32_t u; float f; } v; v.u = u & 0xffff0000u;
    return v.f;
}

// ---------------------------------------------------------------------------
// prep: memory[576][128] f32 -> Bt2 bf16 chunks: chunk cid=(kc*2+hi), 128 n's,
// 16B per n = 8 channels c = (kc&3)*16 + hi*8 + j, q = kc>>2 (kh*3+kw).
// ---------------------------------------------------------------------------
__global__ void prep_b2(const float* __restrict__ mem, uint4* __restrict__ Bt2) {
    int u = blockIdx.x * 256 + threadIdx.x;   // 0..9215
    int n = u & 127;
    int cid = u >> 7;                         // 0..71
    int hi = cid & 1;
    int kc = cid >> 1;                        // 0..35
    int q = kc >> 2, cblk = kc & 3;
    unsigned short h8[8];
#pragma unroll
    for (int j = 0; j < 8; j++) {
        int c = cblk * 16 + hi * 8 + j;
        h8[j] = f2bf(mem[(c * 9 + q) * OC + n]);
    }
    Bt2[cid * 128 + n] = *(const uint4*)h8;
}

// ---------------------------------------------------------------------------
__global__ __launch_bounds__(512, 4) void convf(const float* __restrict__ x,
                                                const uint4* __restrict__ Bt2,
                                                float* __restrict__ out) {
    __shared__ __align__(16) uint4 EtL[180 * 8];   // 23040 B, [p][slot], 10x18 halo
    __shared__ float Sh[180];

    int bid0 = blockIdx.x;
    int bid = ((bid0 & 7) << 7) | (bid0 >> 3);   // XCD chunk swizzle, 1024 = 8*128
    int b = bid >> 7;                            // 8 b * 16 ty * 8 tx
    int ty = (bid >> 3) & 15, tx = bid & 7;
    int h0 = ty * 8, w0 = tx * 16;
    int t = threadIdx.x;
    int lane = t & 63, wid = t >> 6;

    // ---- K-loop geometry (needed now: W prefetch starts before staging) ----
    int wo = wid & 3;                 // oc 32-block
    int wp = wid >> 2;                // px-pair 0..1
    int l31 = lane & 31, hi = lane >> 5;
    int x0v = l31 & 15;
    int y00 = (wp * 2 + 0) * 2 + (l31 >> 4);
    int y01 = (wp * 2 + 1) * 2 + (l31 >> 4);

    auto LW = [&](int kc) -> bf16x8_t {
        return *(const bf16x8_t*)(Bt2 + (size_t)((kc * 2 + hi) * 128 + wo * 32 + l31));
    };
    auto LE = [&](int kc, int y0j) -> bf16x8_t {
        int q = kc >> 2, cblk = kc & 3;
        int kh = q / 3, kw = q - kh * 3;
        int pix = (y0j + kh) * 18 + (x0v + kw);
        return *(const bf16x8_t*)&EtL[pix * 8 + ((cblk * 2 + hi) ^ (pix & 7))];
    };

    // issue 6 W loads immediately — they complete while staging runs
    bf16x8_t W0 = LW(0), W1 = LW(1), W2 = LW(2), W3 = LW(3), W4 = LW(4), W5 = LW(5);

    const float* xb = x + (size_t)b * Cn * HW;

    // ---- staging: 480 items = pg(60 = py10 x qs6) x g(8), g = t&7 so the 8
    //      granule-threads of one pixel-group are lane-adjacent (shfl reduce).
    if (t < 480) {
        int g = t & 7;                    // granule = channels 8g..8g+7
        int pg = t >> 3;                  // 0..59
        int py = pg / 6, qs = pg % 6;
        int gy = h0 - 1 + py;
        bool inrow = (gy >= 0) & (gy < Hn);

        if (qs >= 1 && qs <= 4) {         // core: 4 px, halo px = (qs-1)*4+1 ..
            int px0 = (qs - 1) * 4 + 1;
            float4 v[8];
            if (inrow) {
                const float* basep = xb + (size_t)(8 * g) * HW
                                   + (size_t)gy * Wn + (w0 + (qs - 1) * 4);
#pragma unroll
                for (int k = 0; k < 8; k++)
                    v[k] = *(const float4*)(basep + (size_t)k * HW);
            }
            float s4[4];
#pragma unroll
            for (int i = 0; i < 4; i++) {
                uint32_t wd[4];
                float si;
                if (inrow) {
                    si = 0.f;
#pragma unroll
                    for (int j = 0; j < 4; j++) {
                        float a = ((const float*)&v[2 * j])[i];
                        float c = ((const float*)&v[2 * j + 1])[i];
                        uint32_t pk = (uint32_t)f2bf(__expf(a))
                                    | ((uint32_t)f2bf(__expf(c)) << 16);
                        wd[j] = pk;
                        si += bf_lo(pk) + bf_hi(pk);
                    }
                } else {
                    wd[0] = wd[1] = wd[2] = wd[3] = 0x3F803F80u;
                    si = 8.f;
                }
                int p = py * 18 + px0 + i;
                EtL[p * 8 + (g ^ (p & 7))] = *(const uint4*)wd;
                s4[i] = si;
            }
            // 8-lane granule reduce -> 64-channel sums for the 4 px
#pragma unroll
            for (int m = 1; m < 8; m <<= 1) {
#pragma unroll
                for (int i = 0; i < 4; i++)
                    s4[i] += __shfl_xor(s4[i], m);
            }
            if (g < 4) Sh[py * 18 + px0 + g] = s4[g];
        } else {                          // edge: 1 px, halo px 0 or 17
            int side = (qs == 5);
            int p = py * 18 + (side ? 17 : 0);
            int gxe = side ? (w0 + 16) : (w0 - 1);
            bool real = inrow && (gxe >= 0) && (gxe < Wn);
            uint32_t wd[4];
            float s;
            if (real) {
                const float* basep = xb + (size_t)(8 * g) * HW
                                   + (size_t)gy * Wn + gxe;
                s = 0.f;
#pragma unroll
                for (int j = 0; j < 4; j++) {
                    float a = basep[(size_t)(2 * j) * HW];
                    float c = basep[(size_t)(2 * j + 1) * HW];
                    uint32_t pk = (uint32_t)f2bf(__expf(a))
                                | ((uint32_t)f2bf(__expf(c)) << 16);
                    wd[j] = pk;
                    s += bf_lo(pk) + bf_hi(pk);
                }
            } else {
                wd[0] = wd[1] = wd[2] = wd[3] = 0x3F803F80u;
                s = 8.f;
            }
            EtL[p * 8 + (g ^ (p & 7))] = *(const uint4*)wd;
#pragma unroll
            for (int m = 1; m < 8; m <<= 1)
                s += __shfl_xor(s, m);
            if (g == 0) Sh[p] = s;
        }
    }
    __syncthreads();

    // ---- MFMA K-loop: named slots only (no register arrays -> no scratch).
    //      W ring depth 6 (global/L2), E ring depth 3 (LDS), acc = a0,a1.
    f32x16_t a0, a1;
#pragma unroll
    for (int r = 0; r < 16; r++) { a0[r] = 0.f; a1[r] = 0.f; }

    bf16x8_t E00 = LE(0, y00), E01 = LE(0, y01);
    bf16x8_t E10 = LE(1, y00), E11 = LE(1, y01);
    bf16x8_t E20 = LE(2, y00), E21 = LE(2, y01);

#define KSTEP(WREG, EA, EB)                                                   \
    __builtin_amdgcn_s_setprio(1);                                            \
    a0 = __builtin_amdgcn_mfma_f32_32x32x16_bf16(WREG, EA, a0, 0, 0, 0);      \
    a1 = __builtin_amdgcn_mfma_f32_32x32x16_bf16(WREG, EB, a1, 0, 0, 0);      \
    __builtin_amdgcn_s_setprio(0);

    // 5 full groups of 6 steps: kc = 6*g6 .. 6*g6+5.
    // W prefetch target max = 6*4+11 = 35; E target max = 6*4+8 = 32. Both valid.
    for (int g6 = 0; g6 < 5; ++g6) {
        int kc = g6 * 6;
        KSTEP(W0, E00, E01)  W0 = LW(kc + 6);  E00 = LE(kc + 3, y00); E01 = LE(kc + 3, y01);
        KSTEP(W1, E10, E11)  W1 = LW(kc + 7);  E10 = LE(kc + 4, y00); E11 = LE(kc + 4, y01);
        KSTEP(W2, E20, E21)  W2 = LW(kc + 8);  E20 = LE(kc + 5, y00); E21 = LE(kc + 5, y01);
        KSTEP(W3, E00, E01)  W3 = LW(kc + 9);  E00 = LE(kc + 6, y00); E01 = LE(kc + 6, y01);
        KSTEP(W4, E10, E11)  W4 = LW(kc + 10); E10 = LE(kc + 7, y00); E11 = LE(kc + 7, y01);
        KSTEP(W5, E20, E21)  W5 = LW(kc + 11); E20 = LE(kc + 8, y00); E21 = LE(kc + 8, y01);
    }
    // tail: kc = 30..35 (E prefetch 33..35 only, no W prefetch)
    KSTEP(W0, E00, E01)  E00 = LE(33, y00); E01 = LE(33, y01);
    KSTEP(W1, E10, E11)  E10 = LE(34, y00); E11 = LE(34, y01);
    KSTEP(W2, E20, E21)  E20 = LE(35, y00); E21 = LE(35, y01);
    KSTEP(W3, E00, E01)
    KSTEP(W4, E10, E11)
    KSTEP(W5, E20, E21)
#undef KSTEP

    // ---- epilogue: inline Zinv (3x3 boxsum of Sh), then scaled stores ----
    {
        float z = 0.f;
#pragma unroll
        for (int dy = 0; dy < 3; dy++)
#pragma unroll
            for (int dx = 0; dx < 3; dx++)
                z += Sh[(y00 + dy) * 18 + (x0v + dx)];
        float zi = 1.0f / z;
        float* ob = out + (size_t)b * OC * HW + (size_t)(wo * 32 + 4 * hi) * HW
                  + (h0 + y00) * Wn + (w0 + x0v);
#pragma unroll
        for (int r = 0; r < 16; r++) {
            int nrel = (r & 3) + 8 * (r >> 2);   // + 4*hi folded into ob
            ob[(size_t)nrel * HW] = a0[r] * zi;
        }
    }
    {
        float z = 0.f;
#pragma unroll
        for (int dy = 0; dy < 3; dy++)
#pragma unroll
            for (int dx = 0; dx < 3; dx++)
                z += Sh[(y01 + dy) * 18 + (x0v + dx)];
        float zi = 1.0f / z;
        float* ob = out + (size_t)b * OC * HW + (size_t)(wo * 32 + 4 * hi) * HW
                  + (h0 + y01) * Wn + (w0 + x0v);
#pragma unroll
        for (int r = 0; r < 16; r++) {
            int nrel = (r & 3) + 8 * (r >> 2);
            ob[(size_t)nrel * HW] = a1[r] * zi;
        }
    }
}

// ---------------------------------------------------------------------------
extern "C" void kernel_launch(void* const* d_in, const int* in_sizes, int n_in,
                              void* d_out, int out_size, void* d_ws, size_t ws_size,
                              hipStream_t stream) {
    const float* x = (const float*)d_in[0];
    const float* mem = (const float*)d_in[1];
    float* out = (float*)d_out;

    uint4* Bt2 = (uint4*)d_ws;                 // 147,456 B

    prep_b2<<<36, 256, 0, stream>>>(mem, Bt2);
    convf<<<1024, 512, 0, stream>>>(x, Bt2, out);
}

// Round 8
// 165.199 us; speedup vs baseline: 2.0480x; 2.0480x over previous
//
#include <hip/hip_runtime.h>
#include <stdint.h>

// ConvMemory v9: out = (3x3 conv of E=exp(x), W=memory) / (3x3 boxsum of chan-sum(E))
// Zero-padding before softmax => OOB taps contribute exp(0)=1 to num & denom.
// Fused convf, 8x16 tile, 512 thr (8 waves), 1024 blocks (XCD-chunk swizzled).
// v9 = v8 with ONE change: __launch_bounds__(512, 2) instead of (512, 4).
// Evidence (r7): (512,4) caps VGPR at 64 (measured 60-64 every round using it);
// v8's 12 named bf16x8 slots + 2 f32x16 acc overflowed the cap -> massive
// scratch traffic (FETCH 255MB / WRITE 538MB, 272us). (512,2) raises the cap
// to >=128 so the named-slot deep-prefetch K-loop can actually live in regs.
// Structure (unchanged from v8): named slots W0..W5 / E00..E21 / a0,a1 (no
// runtime-indexed register arrays), W ring 6 issued at KERNEL ENTRY (flies
// during staging), E ring 3 from LDS, single barrier, per-pixel S via 8-lane
// __shfl_xor during staging, Zinv inlined in epilogue.

#define Cn 64
#define Hn 128
#define Wn 128
#define OC 128
#define HW (Hn * Wn)

typedef __attribute__((ext_vector_type(8))) short bf16x8_t;
typedef __attribute__((ext_vector_type(16))) float f32x16_t;

__device__ inline unsigned short f2bf(float f) {
    union { float f; uint32_t u; } v; v.f = f;
    uint32_t u = v.u;
    u += 0x7fffu + ((u >> 16) & 1u);
    return (unsigned short)(u >> 16);
}
__device__ inline float bf_lo(uint32_t u) {
    union { uint32_t u; float f; } v; v.u = u << 16;
    return v.f;
}
__device__ inline float bf_hi(uint32_t u) {
    union { uint32_t u; float f; } v; v.u = u & 0xffff0000u;
    return v.f;
}

// ---------------------------------------------------------------------------
// prep: memory[576][128] f32 -> Bt2 bf16 chunks: chunk cid=(kc*2+hi), 128 n's,
// 16B per n = 8 channels c = (kc&3)*16 + hi*8 + j, q = kc>>2 (kh*3+kw).
// ---------------------------------------------------------------------------
__global__ void prep_b2(const float* __restrict__ mem, uint4* __restrict__ Bt2) {
    int u = blockIdx.x * 256 + threadIdx.x;   // 0..9215
    int n = u & 127;
    int cid = u >> 7;                         // 0..71
    int hi = cid & 1;
    int kc = cid >> 1;                        // 0..35
    int q = kc >> 2, cblk = kc & 3;
    unsigned short h8[8];
#pragma unroll
    for (int j = 0; j < 8; j++) {
        int c = cblk * 16 + hi * 8 + j;
        h8[j] = f2bf(mem[(c * 9 + q) * OC + n]);
    }
    Bt2[cid * 128 + n] = *(const uint4*)h8;
}

// ---------------------------------------------------------------------------
__global__ __launch_bounds__(512, 2) void convf(const float* __restrict__ x,
                                                const uint4* __restrict__ Bt2,
                                                float* __restrict__ out) {
    __shared__ __align__(16) uint4 EtL[180 * 8];   // 23040 B, [p][slot], 10x18 halo
    __shared__ float Sh[180];

    int bid0 = blockIdx.x;
    int bid = ((bid0 & 7) << 7) | (bid0 >> 3);   // XCD chunk swizzle, 1024 = 8*128
    int b = bid >> 7;                            // 8 b * 16 ty * 8 tx
    int ty = (bid >> 3) & 15, tx = bid & 7;
    int h0 = ty * 8, w0 = tx * 16;
    int t = threadIdx.x;
    int lane = t & 63, wid = t >> 6;

    // ---- K-loop geometry (needed now: W prefetch starts before staging) ----
    int wo = wid & 3;                 // oc 32-block
    int wp = wid >> 2;                // px-pair 0..1
    int l31 = lane & 31, hi = lane >> 5;
    int x0v = l31 & 15;
    int y00 = (wp * 2 + 0) * 2 + (l31 >> 4);
    int y01 = (wp * 2 + 1) * 2 + (l31 >> 4);

    auto LW = [&](int kc) -> bf16x8_t {
        return *(const bf16x8_t*)(Bt2 + (size_t)((kc * 2 + hi) * 128 + wo * 32 + l31));
    };
    auto LE = [&](int kc, int y0j) -> bf16x8_t {
        int q = kc >> 2, cblk = kc & 3;
        int kh = q / 3, kw = q - kh * 3;
        int pix = (y0j + kh) * 18 + (x0v + kw);
        return *(const bf16x8_t*)&EtL[pix * 8 + ((cblk * 2 + hi) ^ (pix & 7))];
    };

    // issue 6 W loads immediately — they complete while staging runs
    bf16x8_t W0 = LW(0), W1 = LW(1), W2 = LW(2), W3 = LW(3), W4 = LW(4), W5 = LW(5);

    const float* xb = x + (size_t)b * Cn * HW;

    // ---- staging: 480 items = pg(60 = py10 x qs6) x g(8), g = t&7 so the 8
    //      granule-threads of one pixel-group are lane-adjacent (shfl reduce).
    if (t < 480) {
        int g = t & 7;                    // granule = channels 8g..8g+7
        int pg = t >> 3;                  // 0..59
        int py = pg / 6, qs = pg % 6;
        int gy = h0 - 1 + py;
        bool inrow = (gy >= 0) & (gy < Hn);

        if (qs >= 1 && qs <= 4) {         // core: 4 px, halo px = (qs-1)*4+1 ..
            int px0 = (qs - 1) * 4 + 1;
            float4 v[8];
            if (inrow) {
                const float* basep = xb + (size_t)(8 * g) * HW
                                   + (size_t)gy * Wn + (w0 + (qs - 1) * 4);
#pragma unroll
                for (int k = 0; k < 8; k++)
                    v[k] = *(const float4*)(basep + (size_t)k * HW);
            }
            float s4[4];
#pragma unroll
            for (int i = 0; i < 4; i++) {
                uint32_t wd[4];
                float si;
                if (inrow) {
                    si = 0.f;
#pragma unroll
                    for (int j = 0; j < 4; j++) {
                        float a = ((const float*)&v[2 * j])[i];
                        float c = ((const float*)&v[2 * j + 1])[i];
                        uint32_t pk = (uint32_t)f2bf(__expf(a))
                                    | ((uint32_t)f2bf(__expf(c)) << 16);
                        wd[j] = pk;
                        si += bf_lo(pk) + bf_hi(pk);
                    }
                } else {
                    wd[0] = wd[1] = wd[2] = wd[3] = 0x3F803F80u;
                    si = 8.f;
                }
                int p = py * 18 + px0 + i;
                EtL[p * 8 + (g ^ (p & 7))] = *(const uint4*)wd;
                s4[i] = si;
            }
            // 8-lane granule reduce -> 64-channel sums for the 4 px
#pragma unroll
            for (int m = 1; m < 8; m <<= 1) {
#pragma unroll
                for (int i = 0; i < 4; i++)
                    s4[i] += __shfl_xor(s4[i], m);
            }
            if (g < 4) Sh[py * 18 + px0 + g] = s4[g];
        } else {                          // edge: 1 px, halo px 0 or 17
            int side = (qs == 5);
            int p = py * 18 + (side ? 17 : 0);
            int gxe = side ? (w0 + 16) : (w0 - 1);
            bool real = inrow && (gxe >= 0) && (gxe < Wn);
            uint32_t wd[4];
            float s;
            if (real) {
                const float* basep = xb + (size_t)(8 * g) * HW
                                   + (size_t)gy * Wn + gxe;
                s = 0.f;
#pragma unroll
                for (int j = 0; j < 4; j++) {
                    float a = basep[(size_t)(2 * j) * HW];
                    float c = basep[(size_t)(2 * j + 1) * HW];
                    uint32_t pk = (uint32_t)f2bf(__expf(a))
                                | ((uint32_t)f2bf(__expf(c)) << 16);
                    wd[j] = pk;
                    s += bf_lo(pk) + bf_hi(pk);
                }
            } else {
                wd[0] = wd[1] = wd[2] = wd[3] = 0x3F803F80u;
                s = 8.f;
            }
            EtL[p * 8 + (g ^ (p & 7))] = *(const uint4*)wd;
#pragma unroll
            for (int m = 1; m < 8; m <<= 1)
                s += __shfl_xor(s, m);
            if (g == 0) Sh[p] = s;
        }
    }
    __syncthreads();

    // ---- MFMA K-loop: named slots only (no register arrays -> no scratch).
    //      W ring depth 6 (global/L2), E ring depth 3 (LDS), acc = a0,a1.
    f32x16_t a0, a1;
#pragma unroll
    for (int r = 0; r < 16; r++) { a0[r] = 0.f; a1[r] = 0.f; }

    bf16x8_t E00 = LE(0, y00), E01 = LE(0, y01);
    bf16x8_t E10 = LE(1, y00), E11 = LE(1, y01);
    bf16x8_t E20 = LE(2, y00), E21 = LE(2, y01);

#define KSTEP(WREG, EA, EB)                                                   \
    __builtin_amdgcn_s_setprio(1);                                            \
    a0 = __builtin_amdgcn_mfma_f32_32x32x16_bf16(WREG, EA, a0, 0, 0, 0);      \
    a1 = __builtin_amdgcn_mfma_f32_32x32x16_bf16(WREG, EB, a1, 0, 0, 0);      \
    __builtin_amdgcn_s_setprio(0);

    // 5 full groups of 6 steps: kc = 6*g6 .. 6*g6+5.
    // W prefetch target max = 6*4+11 = 35; E target max = 6*4+8 = 32. Both valid.
    for (int g6 = 0; g6 < 5; ++g6) {
        int kc = g6 * 6;
        KSTEP(W0, E00, E01)  W0 = LW(kc + 6);  E00 = LE(kc + 3, y00); E01 = LE(kc + 3, y01);
        KSTEP(W1, E10, E11)  W1 = LW(kc + 7);  E10 = LE(kc + 4, y00); E11 = LE(kc + 4, y01);
        KSTEP(W2, E20, E21)  W2 = LW(kc + 8);  E20 = LE(kc + 5, y00); E21 = LE(kc + 5, y01);
        KSTEP(W3, E00, E01)  W3 = LW(kc + 9);  E00 = LE(kc + 6, y00); E01 = LE(kc + 6, y01);
        KSTEP(W4, E10, E11)  W4 = LW(kc + 10); E10 = LE(kc + 7, y00); E11 = LE(kc + 7, y01);
        KSTEP(W5, E20, E21)  W5 = LW(kc + 11); E20 = LE(kc + 8, y00); E21 = LE(kc + 8, y01);
    }
    // tail: kc = 30..35 (E prefetch 33..35 only, no W prefetch)
    KSTEP(W0, E00, E01)  E00 = LE(33, y00); E01 = LE(33, y01);
    KSTEP(W1, E10, E11)  E10 = LE(34, y00); E11 = LE(34, y01);
    KSTEP(W2, E20, E21)  E20 = LE(35, y00); E21 = LE(35, y01);
    KSTEP(W3, E00, E01)
    KSTEP(W4, E10, E11)
    KSTEP(W5, E20, E21)
#undef KSTEP

    // ---- epilogue: inline Zinv (3x3 boxsum of Sh), then scaled stores ----
    {
        float z = 0.f;
#pragma unroll
        for (int dy = 0; dy < 3; dy++)
#pragma unroll
            for (int dx = 0; dx < 3; dx++)
                z += Sh[(y00 + dy) * 18 + (x0v + dx)];
        float zi = 1.0f / z;
        float* ob = out + (size_t)b * OC * HW + (size_t)(wo * 32 + 4 * hi) * HW
                  + (h0 + y00) * Wn + (w0 + x0v);
#pragma unroll
        for (int r = 0; r < 16; r++) {
            int nrel = (r & 3) + 8 * (r >> 2);   // + 4*hi folded into ob
            ob[(size_t)nrel * HW] = a0[r] * zi;
        }
    }
    {
        float z = 0.f;
#pragma unroll
        for (int dy = 0; dy < 3; dy++)
#pragma unroll
            for (int dx = 0; dx < 3; dx++)
                z += Sh[(y01 + dy) * 18 + (x0v + dx)];
        float zi = 1.0f / z;
        float* ob = out + (size_t)b * OC * HW + (size_t)(wo * 32 + 4 * hi) * HW
                  + (h0 + y01) * Wn + (w0 + x0v);
#pragma unroll
        for (int r = 0; r < 16; r++) {
            int nrel = (r & 3) + 8 * (r >> 2);
            ob[(size_t)nrel * HW] = a1[r] * zi;
        }
    }
}

// ---------------------------------------------------------------------------
extern "C" void kernel_launch(void* const* d_in, const int* in_sizes, int n_in,
                              void* d_out, int out_size, void* d_ws, size_t ws_size,
                              hipStream_t stream) {
    const float* x = (const float*)d_in[0];
    const float* mem = (const float*)d_in[1];
    float* out = (float*)d_out;

    uint4* Bt2 = (uint4*)d_ws;                 // 147,456 B

    prep_b2<<<36, 256, 0, stream>>>(mem, Bt2);
    convf<<<1024, 512, 0, stream>>>(x, Bt2, out);
}